// Round 5
// baseline (669.742 us; speedup 1.0000x reference)
//
#include <hip/hip_runtime.h>

// PathGCN fused layer — fp32.
// out[n,j] = relu( sum_k res[n,k] * fcw[j,k] )
// res[n,k] = (1/8) * sum_l pw[l,k] * ( sum_p feats[ paths[p,n,l], k ] )
//
// R5: decouple gather from GEMM. Evidence: R1's spilled kernel sustained
// 4.33 TB/s EA traffic (same random-gather pattern) while R0/R4 sit at
// 3.6-3.8 TB/s; R4 raised occupancy 45->57% yet got SLOWER with 2x barriers.
// => binding constraint is gather loads-in-flight, drained by phase-2
// barriers, not wave residency. Kernel A: gather+einsum only (1 barrier,
// 2 KB LDS, res -> d_ws). Kernel B: R0's proven phase-2 (KT=32 pad-33,
// zero conflicts) as a standalone streaming GEMM+ReLU. Fallback to fused
// R0 kernel if workspace is too small.

#define N_NODES 100000
#define HIDDEN  128
#define NPATH   8
#define PLEN    8
#define NPB     8      // nodes per block (256 threads = 8 nodes x 32 lanes)
#define KT      32     // k-tile width for fcw staging (kernel B / fused)

// ---------------- Kernel A: gather + path-weight einsum -> res ----------------
__global__ void PathGCNLayer_61306363183203_gather(
    const float4* __restrict__ feats4,   // (N, 32) float4 rows
    const int*    __restrict__ paths,    // (8, N, 8) int32
    const float4* __restrict__ pw4,      // (8, 32) float4 rows
    float4*       __restrict__ res4)     // (N, 32) float4 rows (workspace)
{
    __shared__ int sidx[NPATH * NPB * PLEN];   // [p][node][l], p-major (2 KB)

    const int tid  = threadIdx.x;
    const int n0   = blockIdx.x * NPB;
    const int node = tid >> 5;      // 0..7
    const int c    = tid & 31;      // float4 column within row

    // stage 512 path indices (for each p: 64 consecutive ints)
    {
        const int p = tid >> 5;     // 0..7
        const int i = tid & 31;
        const size_t base = (size_t)p * (N_NODES * PLEN) + (size_t)n0 * PLEN;
        sidx[p * 64 + i]      = paths[base + i];
        sidx[p * 64 + i + 32] = paths[base + i + 32];
    }
    __syncthreads();   // the ONLY barrier — gather loop below never stalls on block-mates

    float ax = 0.0f, ay = 0.0f, az = 0.0f, aw = 0.0f;
    #pragma unroll
    for (int l = 0; l < PLEN; ++l) {
        float sx = 0.0f, sy = 0.0f, sz = 0.0f, sw = 0.0f;
        #pragma unroll
        for (int p = 0; p < NPATH; ++p) {
            const int idx = sidx[p * 64 + node * PLEN + l];
            const float4 v = feats4[(size_t)idx * 32 + c];
            sx += v.x; sy += v.y; sz += v.z; sw += v.w;
        }
        const float4 w = pw4[l * 32 + c];
        ax = fmaf(sx, w.x, ax);
        ay = fmaf(sy, w.y, ay);
        az = fmaf(sz, w.z, az);
        aw = fmaf(sw, w.w, aw);
    }

    float4 r;
    r.x = ax * 0.125f; r.y = ay * 0.125f;
    r.z = az * 0.125f; r.w = aw * 0.125f;
    res4[(size_t)(n0 + node) * 32 + c] = r;   // 2 rows x 512 B per wave instr, coalesced
}

// ---------------- Kernel B: out = relu(res @ fcw^T), streaming GEMM ----------------
__global__ void PathGCNLayer_61306363183203_gemm(
    const float4* __restrict__ res4,     // (N, 32) float4 rows (workspace)
    const float4* __restrict__ fcw4,     // (128, 32) float4 rows
    float*        __restrict__ out)      // (N, 128) f32
{
    __shared__ float4 sres4[NPB][33];            // res tile, pad breaks stride (4.2 KB)
    __shared__ float  fcwt[HIDDEN][KT + 1];      // fcw k-tile, pad 33 -> conflict-free (16.9 KB)

    const int tid  = threadIdx.x;
    const int n0   = blockIdx.x * NPB;
    const int node = tid >> 5;      // 0..7
    const int c    = tid & 31;      // float4 column within row

    // stage res tile (coalesced: 2 rows x 512 B per wave instr)
    sres4[node][c] = res4[(size_t)(n0 + node) * 32 + c];

    float o0 = 0.0f, o1 = 0.0f, o2 = 0.0f, o3 = 0.0f;

    #pragma unroll
    for (int kt = 0; kt < HIDDEN / KT; ++kt) {
        __syncthreads();   // protects fcwt reuse; first iter also covers sres writes
        // stage fcw[:, kt*32 .. kt*32+31] -> fcwt[j][k'] (coalesced global)
        {
            const int j    = tid >> 1;        // 0..127
            const int half = tid & 1;         // 0..1
            const int gbase = j * 32 + kt * (KT / 4) + half * 4;
            const int lbase = half * 16;
            #pragma unroll
            for (int q = 0; q < 4; ++q) {
                const float4 v = fcw4[gbase + q];
                fcwt[j][lbase + q * 4 + 0] = v.x;
                fcwt[j][lbase + q * 4 + 1] = v.y;
                fcwt[j][lbase + q * 4 + 2] = v.z;
                fcwt[j][lbase + q * 4 + 3] = v.w;
            }
        }
        __syncthreads();

        #pragma unroll
        for (int kc = 0; kc < KT / 4; ++kc) {
            const float4 rv = sres4[node][kt * (KT / 4) + kc];
            const int k0 = kc * 4;
            o0 = fmaf(rv.x, fcwt[c      ][k0    ], o0);
            o1 = fmaf(rv.x, fcwt[c + 32 ][k0    ], o1);
            o2 = fmaf(rv.x, fcwt[c + 64 ][k0    ], o2);
            o3 = fmaf(rv.x, fcwt[c + 96 ][k0    ], o3);
            o0 = fmaf(rv.y, fcwt[c      ][k0 + 1], o0);
            o1 = fmaf(rv.y, fcwt[c + 32 ][k0 + 1], o1);
            o2 = fmaf(rv.y, fcwt[c + 64 ][k0 + 1], o2);
            o3 = fmaf(rv.y, fcwt[c + 96 ][k0 + 1], o3);
            o0 = fmaf(rv.z, fcwt[c      ][k0 + 2], o0);
            o1 = fmaf(rv.z, fcwt[c + 32 ][k0 + 2], o1);
            o2 = fmaf(rv.z, fcwt[c + 64 ][k0 + 2], o2);
            o3 = fmaf(rv.z, fcwt[c + 96 ][k0 + 2], o3);
            o0 = fmaf(rv.w, fcwt[c      ][k0 + 3], o0);
            o1 = fmaf(rv.w, fcwt[c + 32 ][k0 + 3], o1);
            o2 = fmaf(rv.w, fcwt[c + 64 ][k0 + 3], o2);
            o3 = fmaf(rv.w, fcwt[c + 96 ][k0 + 3], o3);
        }
    }

    {
        const size_t obase = (size_t)(n0 + node) * HIDDEN + c;
        out[obase]      = o0 > 0.0f ? o0 : 0.0f;
        out[obase + 32] = o1 > 0.0f ? o1 : 0.0f;
        out[obase + 64] = o2 > 0.0f ? o2 : 0.0f;
        out[obase + 96] = o3 > 0.0f ? o3 : 0.0f;
    }
}

// ---------------- Fallback: R0's fused kernel (418 us proven) ----------------
__global__ void PathGCNLayer_61306363183203_fused(
    const float4* __restrict__ feats4,
    const int*    __restrict__ paths,
    const float4* __restrict__ pw4,
    const float4* __restrict__ fcw4,
    float*        __restrict__ out)
{
    __shared__ int    sidx[NPATH * NPB * PLEN];
    __shared__ float4 sres4[NPB][33];
    __shared__ float  fcwt[HIDDEN][KT + 1];

    const int tid  = threadIdx.x;
    const int n0   = blockIdx.x * NPB;
    const int node = tid >> 5;
    const int c    = tid & 31;

    {
        const int p = tid >> 5;
        const int i = tid & 31;
        const size_t base = (size_t)p * (N_NODES * PLEN) + (size_t)n0 * PLEN;
        sidx[p * 64 + i]      = paths[base + i];
        sidx[p * 64 + i + 32] = paths[base + i + 32];
    }
    __syncthreads();

    float ax = 0.0f, ay = 0.0f, az = 0.0f, aw = 0.0f;
    #pragma unroll
    for (int l = 0; l < PLEN; ++l) {
        float sx = 0.0f, sy = 0.0f, sz = 0.0f, sw = 0.0f;
        #pragma unroll
        for (int p = 0; p < NPATH; ++p) {
            const int idx = sidx[p * 64 + node * PLEN + l];
            const float4 v = feats4[(size_t)idx * 32 + c];
            sx += v.x; sy += v.y; sz += v.z; sw += v.w;
        }
        const float4 w = pw4[l * 32 + c];
        ax = fmaf(sx, w.x, ax);
        ay = fmaf(sy, w.y, ay);
        az = fmaf(sz, w.z, az);
        aw = fmaf(sw, w.w, aw);
    }
    {
        float4 r;
        r.x = ax * 0.125f; r.y = ay * 0.125f;
        r.z = az * 0.125f; r.w = aw * 0.125f;
        sres4[node][c] = r;
    }

    float o0 = 0.0f, o1 = 0.0f, o2 = 0.0f, o3 = 0.0f;
    #pragma unroll
    for (int kt = 0; kt < HIDDEN / KT; ++kt) {
        __syncthreads();
        {
            const int j    = tid >> 1;
            const int half = tid & 1;
            const int gbase = j * 32 + kt * (KT / 4) + half * 4;
            const int lbase = half * 16;
            #pragma unroll
            for (int q = 0; q < 4; ++q) {
                const float4 v = fcw4[gbase + q];
                fcwt[j][lbase + q * 4 + 0] = v.x;
                fcwt[j][lbase + q * 4 + 1] = v.y;
                fcwt[j][lbase + q * 4 + 2] = v.z;
                fcwt[j][lbase + q * 4 + 3] = v.w;
            }
        }
        __syncthreads();
        #pragma unroll
        for (int kc = 0; kc < KT / 4; ++kc) {
            const float4 rv = sres4[node][kt * (KT / 4) + kc];
            const int k0 = kc * 4;
            o0 = fmaf(rv.x, fcwt[c      ][k0    ], o0);
            o1 = fmaf(rv.x, fcwt[c + 32 ][k0    ], o1);
            o2 = fmaf(rv.x, fcwt[c + 64 ][k0    ], o2);
            o3 = fmaf(rv.x, fcwt[c + 96 ][k0    ], o3);
            o0 = fmaf(rv.y, fcwt[c      ][k0 + 1], o0);
            o1 = fmaf(rv.y, fcwt[c + 32 ][k0 + 1], o1);
            o2 = fmaf(rv.y, fcwt[c + 64 ][k0 + 1], o2);
            o3 = fmaf(rv.y, fcwt[c + 96 ][k0 + 1], o3);
            o0 = fmaf(rv.z, fcwt[c      ][k0 + 2], o0);
            o1 = fmaf(rv.z, fcwt[c + 32 ][k0 + 2], o1);
            o2 = fmaf(rv.z, fcwt[c + 64 ][k0 + 2], o2);
            o3 = fmaf(rv.z, fcwt[c + 96 ][k0 + 2], o3);
            o0 = fmaf(rv.w, fcwt[c      ][k0 + 3], o0);
            o1 = fmaf(rv.w, fcwt[c + 32 ][k0 + 3], o1);
            o2 = fmaf(rv.w, fcwt[c + 64 ][k0 + 3], o2);
            o3 = fmaf(rv.w, fcwt[c + 96 ][k0 + 3], o3);
        }
    }
    {
        const size_t obase = (size_t)(n0 + node) * HIDDEN + c;
        out[obase]      = o0 > 0.0f ? o0 : 0.0f;
        out[obase + 32] = o1 > 0.0f ? o1 : 0.0f;
        out[obase + 64] = o2 > 0.0f ? o2 : 0.0f;
        out[obase + 96] = o3 > 0.0f ? o3 : 0.0f;
    }
}

extern "C" void kernel_launch(void* const* d_in, const int* in_sizes, int n_in,
                              void* d_out, int out_size, void* d_ws, size_t ws_size,
                              hipStream_t stream) {
    const float4* feats4 = (const float4*)d_in[0];  // (N,128) f32
    const int*    paths  = (const int*)d_in[1];     // (8,N,8) int32
    // d_in[2] = init_feats — unused by the reference
    const float4* pw4    = (const float4*)d_in[3];  // (1,8,128) f32
    const float4* fcw4   = (const float4*)d_in[4];  // (128,128) f32
    float* out = (float*)d_out;
    (void)in_sizes; (void)n_in; (void)out_size;

    const size_t res_bytes = (size_t)N_NODES * HIDDEN * sizeof(float);  // 51.2 MB
    if (d_ws != nullptr && ws_size >= res_bytes) {
        float4* res4 = (float4*)d_ws;
        PathGCNLayer_61306363183203_gather<<<N_NODES / NPB, 256, 0, stream>>>(
            feats4, paths, pw4, res4);
        PathGCNLayer_61306363183203_gemm<<<N_NODES / NPB, 256, 0, stream>>>(
            res4, fcw4, out);
    } else {
        PathGCNLayer_61306363183203_fused<<<N_NODES / NPB, 256, 0, stream>>>(
            feats4, paths, pw4, fcw4, out);
    }
}

// Round 7
// 367.459 us; speedup vs baseline: 1.8226x; 1.8226x over previous
//
#include <hip/hip_runtime.h>
#include <hip/hip_fp16.h>

// PathGCN fused layer — fp32 math, f16 gather operand.
// out[n,j] = relu( sum_k res[n,k] * fcw[j,k] )
// res[n,k] = (1/8) * sum_l pw[l,k] * ( sum_p feats[ paths[p,n,l], k ] )
//
// R7 == R6 resubmit (R6 bench died on container infra pre-launch; kernel
// audited: in-bounds, uniform barriers, graph-capture-safe).
// R6: R5 proved the gather L2-fill path saturates at ~3.6 TB/s regardless of
// occupancy (45/57/62%) or barriers (gather-only kernel == fused kernel time).
// Only lever left: fewer gather bytes. Pre-convert feats f32->f16 into d_ws
// (25.6 MB, ~15us streaming); fused kernel gathers 256 B/row instead of 512.
// f16 rel err 2^-11 -> ~2e-4 worst-case output error vs 3.9e-3 tolerance.
// GEMM phase unchanged (f32, KT=32, pad-33, zero conflicts). Fused (not
// split): R5 showed splitting costs ~240us of lost gather/gemm overlap.

#define N_NODES 100000
#define HIDDEN  128
#define NPATH   8
#define PLEN    8
#define NPB     8      // nodes per block (256 threads = 8 nodes x 32 lanes)
#define KT      32     // k-tile width for fcw staging

// ---------------- Kernel 0: feats f32 -> f16 copy (workspace) ----------------
__global__ void PathGCNLayer_61306363183203_tohalf(
    const float4* __restrict__ feats4,   // (N*32) float4
    uint2*        __restrict__ fh)       // (N*32) uint2 = 4 halfs
{
    const size_t i = (size_t)blockIdx.x * blockDim.x + threadIdx.x;
    if (i < (size_t)N_NODES * 32) {
        const float4 v = feats4[i];
        __half2 a = __floats2half2_rn(v.x, v.y);
        __half2 b = __floats2half2_rn(v.z, v.w);
        uint2 o;
        o.x = *reinterpret_cast<unsigned int*>(&a);
        o.y = *reinterpret_cast<unsigned int*>(&b);
        fh[i] = o;
    }
}

// ---------------- Kernel 1: fused gather(f16) + einsum + GEMM + ReLU ----------------
__global__ void PathGCNLayer_61306363183203_fused_h(
    const uint2*  __restrict__ feats_h,  // (N, 32) uint2 rows (4 halfs each)
    const int*    __restrict__ paths,    // (8, N, 8) int32
    const float4* __restrict__ pw4,      // (8, 32) float4 rows
    const float4* __restrict__ fcw4,     // (128, 32) float4 rows
    float*        __restrict__ out)      // (N, 128) f32
{
    __shared__ int    sidx[NPATH * NPB * PLEN];  // [p][node][l], p-major (2 KB)
    __shared__ float4 sres4[NPB][33];            // res tile, pad breaks stride
    __shared__ float  fcwt[HIDDEN][KT + 1];      // fcw k-tile, pad 33 -> conflict-free

    const int tid  = threadIdx.x;
    const int n0   = blockIdx.x * NPB;
    const int node = tid >> 5;      // 0..7
    const int c    = tid & 31;      // 4-wide column group within row

    // ---- stage 512 path indices (for each p: 64 consecutive ints) ----
    {
        const int p = tid >> 5;     // 0..7
        const int i = tid & 31;
        const size_t base = (size_t)p * (N_NODES * PLEN) + (size_t)n0 * PLEN;
        sidx[p * 64 + i]      = paths[base + i];
        sidx[p * 64 + i + 32] = paths[base + i + 32];
    }
    __syncthreads();

    // ---- phase 1: res[node][4c..4c+3] from f16 feats (256 B/row) ----
    float ax = 0.0f, ay = 0.0f, az = 0.0f, aw = 0.0f;
    #pragma unroll
    for (int l = 0; l < PLEN; ++l) {
        float sx = 0.0f, sy = 0.0f, sz = 0.0f, sw = 0.0f;
        #pragma unroll
        for (int p = 0; p < NPATH; ++p) {
            const int idx = sidx[p * 64 + node * PLEN + l];
            const uint2 hv = feats_h[(size_t)idx * 32 + c];
            const __half2 h0 = *reinterpret_cast<const __half2*>(&hv.x);
            const __half2 h1 = *reinterpret_cast<const __half2*>(&hv.y);
            const float2 f0 = __half22float2(h0);
            const float2 f1 = __half22float2(h1);
            sx += f0.x; sy += f0.y; sz += f1.x; sw += f1.y;
        }
        const float4 w = pw4[l * 32 + c];
        ax = fmaf(sx, w.x, ax);
        ay = fmaf(sy, w.y, ay);
        az = fmaf(sz, w.z, az);
        aw = fmaf(sw, w.w, aw);
    }
    {
        float4 r;
        r.x = ax * 0.125f; r.y = ay * 0.125f;
        r.z = az * 0.125f; r.w = aw * 0.125f;
        sres4[node][c] = r;
    }

    // ---- phase 2: out[node][j], j = c + 32*jj, over 4 fcw k-tiles ----
    float o0 = 0.0f, o1 = 0.0f, o2 = 0.0f, o3 = 0.0f;

    #pragma unroll
    for (int kt = 0; kt < HIDDEN / KT; ++kt) {
        __syncthreads();   // protect fcwt reuse (and sres on first iter)
        {
            const int j    = tid >> 1;        // 0..127
            const int half = tid & 1;         // 0..1
            const int gbase = j * 32 + kt * (KT / 4) + half * 4;
            const int lbase = half * 16;
            #pragma unroll
            for (int q = 0; q < 4; ++q) {
                const float4 v = fcw4[gbase + q];
                fcwt[j][lbase + q * 4 + 0] = v.x;
                fcwt[j][lbase + q * 4 + 1] = v.y;
                fcwt[j][lbase + q * 4 + 2] = v.z;
                fcwt[j][lbase + q * 4 + 3] = v.w;
            }
        }
        __syncthreads();

        #pragma unroll
        for (int kc = 0; kc < KT / 4; ++kc) {
            const float4 rv = sres4[node][kt * (KT / 4) + kc];
            const int k0 = kc * 4;
            o0 = fmaf(rv.x, fcwt[c      ][k0    ], o0);
            o1 = fmaf(rv.x, fcwt[c + 32 ][k0    ], o1);
            o2 = fmaf(rv.x, fcwt[c + 64 ][k0    ], o2);
            o3 = fmaf(rv.x, fcwt[c + 96 ][k0    ], o3);
            o0 = fmaf(rv.y, fcwt[c      ][k0 + 1], o0);
            o1 = fmaf(rv.y, fcwt[c + 32 ][k0 + 1], o1);
            o2 = fmaf(rv.y, fcwt[c + 64 ][k0 + 1], o2);
            o3 = fmaf(rv.y, fcwt[c + 96 ][k0 + 1], o3);
            o0 = fmaf(rv.z, fcwt[c      ][k0 + 2], o0);
            o1 = fmaf(rv.z, fcwt[c + 32 ][k0 + 2], o1);
            o2 = fmaf(rv.z, fcwt[c + 64 ][k0 + 2], o2);
            o3 = fmaf(rv.z, fcwt[c + 96 ][k0 + 2], o3);
            o0 = fmaf(rv.w, fcwt[c      ][k0 + 3], o0);
            o1 = fmaf(rv.w, fcwt[c + 32 ][k0 + 3], o1);
            o2 = fmaf(rv.w, fcwt[c + 64 ][k0 + 3], o2);
            o3 = fmaf(rv.w, fcwt[c + 96 ][k0 + 3], o3);
        }
    }

    {
        const size_t obase = (size_t)(n0 + node) * HIDDEN + c;
        out[obase]      = o0 > 0.0f ? o0 : 0.0f;
        out[obase + 32] = o1 > 0.0f ? o1 : 0.0f;
        out[obase + 64] = o2 > 0.0f ? o2 : 0.0f;
        out[obase + 96] = o3 > 0.0f ? o3 : 0.0f;
    }
}

// ---------------- Fallback: R0's fused f32 kernel (418 us proven) ----------------
__global__ void PathGCNLayer_61306363183203_fused(
    const float4* __restrict__ feats4,
    const int*    __restrict__ paths,
    const float4* __restrict__ pw4,
    const float4* __restrict__ fcw4,
    float*        __restrict__ out)
{
    __shared__ int    sidx[NPATH * NPB * PLEN];
    __shared__ float4 sres4[NPB][33];
    __shared__ float  fcwt[HIDDEN][KT + 1];

    const int tid  = threadIdx.x;
    const int n0   = blockIdx.x * NPB;
    const int node = tid >> 5;
    const int c    = tid & 31;

    {
        const int p = tid >> 5;
        const int i = tid & 31;
        const size_t base = (size_t)p * (N_NODES * PLEN) + (size_t)n0 * PLEN;
        sidx[p * 64 + i]      = paths[base + i];
        sidx[p * 64 + i + 32] = paths[base + i + 32];
    }
    __syncthreads();

    float ax = 0.0f, ay = 0.0f, az = 0.0f, aw = 0.0f;
    #pragma unroll
    for (int l = 0; l < PLEN; ++l) {
        float sx = 0.0f, sy = 0.0f, sz = 0.0f, sw = 0.0f;
        #pragma unroll
        for (int p = 0; p < NPATH; ++p) {
            const int idx = sidx[p * 64 + node * PLEN + l];
            const float4 v = feats4[(size_t)idx * 32 + c];
            sx += v.x; sy += v.y; sz += v.z; sw += v.w;
        }
        const float4 w = pw4[l * 32 + c];
        ax = fmaf(sx, w.x, ax);
        ay = fmaf(sy, w.y, ay);
        az = fmaf(sz, w.z, az);
        aw = fmaf(sw, w.w, aw);
    }
    {
        float4 r;
        r.x = ax * 0.125f; r.y = ay * 0.125f;
        r.z = az * 0.125f; r.w = aw * 0.125f;
        sres4[node][c] = r;
    }

    float o0 = 0.0f, o1 = 0.0f, o2 = 0.0f, o3 = 0.0f;
    #pragma unroll
    for (int kt = 0; kt < HIDDEN / KT; ++kt) {
        __syncthreads();
        {
            const int j    = tid >> 1;
            const int half = tid & 1;
            const int gbase = j * 32 + kt * (KT / 4) + half * 4;
            const int lbase = half * 16;
            #pragma unroll
            for (int q = 0; q < 4; ++q) {
                const float4 v = fcw4[gbase + q];
                fcwt[j][lbase + q * 4 + 0] = v.x;
                fcwt[j][lbase + q * 4 + 1] = v.y;
                fcwt[j][lbase + q * 4 + 2] = v.z;
                fcwt[j][lbase + q * 4 + 3] = v.w;
            }
        }
        __syncthreads();
        #pragma unroll
        for (int kc = 0; kc < KT / 4; ++kc) {
            const float4 rv = sres4[node][kt * (KT / 4) + kc];
            const int k0 = kc * 4;
            o0 = fmaf(rv.x, fcwt[c      ][k0    ], o0);
            o1 = fmaf(rv.x, fcwt[c + 32 ][k0    ], o1);
            o2 = fmaf(rv.x, fcwt[c + 64 ][k0    ], o2);
            o3 = fmaf(rv.x, fcwt[c + 96 ][k0    ], o3);
            o0 = fmaf(rv.y, fcwt[c      ][k0 + 1], o0);
            o1 = fmaf(rv.y, fcwt[c + 32 ][k0 + 1], o1);
            o2 = fmaf(rv.y, fcwt[c + 64 ][k0 + 1], o2);
            o3 = fmaf(rv.y, fcwt[c + 96 ][k0 + 1], o3);
            o0 = fmaf(rv.z, fcwt[c      ][k0 + 2], o0);
            o1 = fmaf(rv.z, fcwt[c + 32 ][k0 + 2], o1);
            o2 = fmaf(rv.z, fcwt[c + 64 ][k0 + 2], o2);
            o3 = fmaf(rv.z, fcwt[c + 96 ][k0 + 2], o3);
            o0 = fmaf(rv.w, fcwt[c      ][k0 + 3], o0);
            o1 = fmaf(rv.w, fcwt[c + 32 ][k0 + 3], o1);
            o2 = fmaf(rv.w, fcwt[c + 64 ][k0 + 3], o2);
            o3 = fmaf(rv.w, fcwt[c + 96 ][k0 + 3], o3);
        }
    }
    {
        const size_t obase = (size_t)(n0 + node) * HIDDEN + c;
        out[obase]      = o0 > 0.0f ? o0 : 0.0f;
        out[obase + 32] = o1 > 0.0f ? o1 : 0.0f;
        out[obase + 64] = o2 > 0.0f ? o2 : 0.0f;
        out[obase + 96] = o3 > 0.0f ? o3 : 0.0f;
    }
}

extern "C" void kernel_launch(void* const* d_in, const int* in_sizes, int n_in,
                              void* d_out, int out_size, void* d_ws, size_t ws_size,
                              hipStream_t stream) {
    const float4* feats4 = (const float4*)d_in[0];  // (N,128) f32
    const int*    paths  = (const int*)d_in[1];     // (8,N,8) int32
    // d_in[2] = init_feats — unused by the reference
    const float4* pw4    = (const float4*)d_in[3];  // (1,8,128) f32
    const float4* fcw4   = (const float4*)d_in[4];  // (128,128) f32
    float* out = (float*)d_out;
    (void)in_sizes; (void)n_in; (void)out_size;

    const size_t half_bytes = (size_t)N_NODES * HIDDEN * sizeof(unsigned short); // 25.6 MB
    if (d_ws != nullptr && ws_size >= half_bytes) {
        uint2* fh = (uint2*)d_ws;
        const int cvt_blocks = (N_NODES * 32 + 255) / 256;   // 3.2M float4s
        PathGCNLayer_61306363183203_tohalf<<<cvt_blocks, 256, 0, stream>>>(feats4, fh);
        PathGCNLayer_61306363183203_fused_h<<<N_NODES / NPB, 256, 0, stream>>>(
            fh, paths, pw4, fcw4, out);
    } else {
        PathGCNLayer_61306363183203_fused<<<N_NODES / NPB, 256, 0, stream>>>(
            feats4, paths, pw4, fcw4, out);
    }
}

// Round 9
// 350.475 us; speedup vs baseline: 1.9110x; 1.0485x over previous
//
#include <hip/hip_runtime.h>
#include <hip/hip_fp16.h>

// PathGCN fused layer — fp32 math, f16 gather operand.
// out[n,j] = relu( sum_k res[n,k] * fcw[j,k] )
// res[n,k] = (1/8) * sum_l pw[l,k] * ( sum_p feats[ paths[p,n,l], k ] )
//
// R9 == R8 with compile fix: __builtin_nontemporal_load(float4*) is invalid
// (HIP_vector_type not scalar/vector) — plain load in tohalf, as in R7.
// R8 theory: force gather MLP. R7 counters (FETCH-path 2.8 TB/s < 3.6
// ceiling, VALU 55%, occ 44% — nothing saturated) + VGPR=52 point at
// per-load serialization. Batch all 8 rows of an l-group into named
// registers before accumulating. No __launch_bounds__ (R1: spills).
// Rest is R7's proven config: f16 feats in d_ws, fused, KT=32 pad-33.

#define N_NODES 100000
#define HIDDEN  128
#define NPATH   8
#define PLEN    8
#define NPB     8      // nodes per block (256 threads = 8 nodes x 32 lanes)
#define KT      32     // k-tile width for fcw staging

// ---------------- Kernel 0: feats f32 -> f16 copy (workspace) ----------------
__global__ void PathGCNLayer_61306363183203_tohalf(
    const float4* __restrict__ feats4,   // (N*32) float4
    uint2*        __restrict__ fh)       // (N*32) uint2 = 4 halfs
{
    const size_t i = (size_t)blockIdx.x * blockDim.x + threadIdx.x;
    if (i < (size_t)N_NODES * 32) {
        const float4 v = feats4[i];
        __half2 a = __floats2half2_rn(v.x, v.y);
        __half2 b = __floats2half2_rn(v.z, v.w);
        uint2 o;
        o.x = *reinterpret_cast<unsigned int*>(&a);
        o.y = *reinterpret_cast<unsigned int*>(&b);
        fh[i] = o;
    }
}

// ---------------- Kernel 1: fused gather(f16) + einsum + GEMM + ReLU ----------------
__global__ void PathGCNLayer_61306363183203_fused_h(
    const uint2*  __restrict__ feats_h,  // (N, 32) uint2 rows (4 halfs each)
    const int*    __restrict__ paths,    // (8, N, 8) int32
    const float4* __restrict__ pw4,      // (8, 32) float4 rows
    const float4* __restrict__ fcw4,     // (128, 32) float4 rows
    float*        __restrict__ out)      // (N, 128) f32
{
    __shared__ int    sidx[NPATH * NPB * PLEN];  // [p][node][l], p-major (2 KB)
    __shared__ float4 sres4[NPB][33];            // res tile, pad breaks stride
    __shared__ float  fcwt[HIDDEN][KT + 1];      // fcw k-tile, pad 33 -> conflict-free

    const int tid  = threadIdx.x;
    const int n0   = blockIdx.x * NPB;
    const int node = tid >> 5;      // 0..7
    const int c    = tid & 31;      // 4-wide column group within row

    // ---- stage 512 path indices (for each p: 64 consecutive ints) ----
    {
        const int p = tid >> 5;     // 0..7
        const int i = tid & 31;
        const size_t base = (size_t)p * (N_NODES * PLEN) + (size_t)n0 * PLEN;
        sidx[p * 64 + i]      = paths[base + i];
        sidx[p * 64 + i + 32] = paths[base + i + 32];
    }
    __syncthreads();

    // ---- phase 1: res[node][4c..4c+3] from f16 feats (256 B/row) ----
    // 8-deep load batch per l-group: all NPATH rows in flight before any
    // accumulate touches them (breaks load->waitcnt->add serialization).
    float2 a01 = {0.0f, 0.0f}, a23 = {0.0f, 0.0f};
    #pragma unroll
    for (int l = 0; l < PLEN; ++l) {
        uint2 hv0, hv1, hv2, hv3, hv4, hv5, hv6, hv7;
        {
            const int i0 = sidx[0 * 64 + node * PLEN + l];
            const int i1 = sidx[1 * 64 + node * PLEN + l];
            const int i2 = sidx[2 * 64 + node * PLEN + l];
            const int i3 = sidx[3 * 64 + node * PLEN + l];
            const int i4 = sidx[4 * 64 + node * PLEN + l];
            const int i5 = sidx[5 * 64 + node * PLEN + l];
            const int i6 = sidx[6 * 64 + node * PLEN + l];
            const int i7 = sidx[7 * 64 + node * PLEN + l];
            hv0 = feats_h[(size_t)i0 * 32 + c];
            hv1 = feats_h[(size_t)i1 * 32 + c];
            hv2 = feats_h[(size_t)i2 * 32 + c];
            hv3 = feats_h[(size_t)i3 * 32 + c];
            hv4 = feats_h[(size_t)i4 * 32 + c];
            hv5 = feats_h[(size_t)i5 * 32 + c];
            hv6 = feats_h[(size_t)i6 * 32 + c];
            hv7 = feats_h[(size_t)i7 * 32 + c];
        }
        float2 s01 = {0.0f, 0.0f}, s23 = {0.0f, 0.0f};
        {
            const float2 f0 = __half22float2(*reinterpret_cast<const __half2*>(&hv0.x));
            const float2 f1 = __half22float2(*reinterpret_cast<const __half2*>(&hv0.y));
            s01.x += f0.x; s01.y += f0.y; s23.x += f1.x; s23.y += f1.y;
        }
        {
            const float2 f0 = __half22float2(*reinterpret_cast<const __half2*>(&hv1.x));
            const float2 f1 = __half22float2(*reinterpret_cast<const __half2*>(&hv1.y));
            s01.x += f0.x; s01.y += f0.y; s23.x += f1.x; s23.y += f1.y;
        }
        {
            const float2 f0 = __half22float2(*reinterpret_cast<const __half2*>(&hv2.x));
            const float2 f1 = __half22float2(*reinterpret_cast<const __half2*>(&hv2.y));
            s01.x += f0.x; s01.y += f0.y; s23.x += f1.x; s23.y += f1.y;
        }
        {
            const float2 f0 = __half22float2(*reinterpret_cast<const __half2*>(&hv3.x));
            const float2 f1 = __half22float2(*reinterpret_cast<const __half2*>(&hv3.y));
            s01.x += f0.x; s01.y += f0.y; s23.x += f1.x; s23.y += f1.y;
        }
        {
            const float2 f0 = __half22float2(*reinterpret_cast<const __half2*>(&hv4.x));
            const float2 f1 = __half22float2(*reinterpret_cast<const __half2*>(&hv4.y));
            s01.x += f0.x; s01.y += f0.y; s23.x += f1.x; s23.y += f1.y;
        }
        {
            const float2 f0 = __half22float2(*reinterpret_cast<const __half2*>(&hv5.x));
            const float2 f1 = __half22float2(*reinterpret_cast<const __half2*>(&hv5.y));
            s01.x += f0.x; s01.y += f0.y; s23.x += f1.x; s23.y += f1.y;
        }
        {
            const float2 f0 = __half22float2(*reinterpret_cast<const __half2*>(&hv6.x));
            const float2 f1 = __half22float2(*reinterpret_cast<const __half2*>(&hv6.y));
            s01.x += f0.x; s01.y += f0.y; s23.x += f1.x; s23.y += f1.y;
        }
        {
            const float2 f0 = __half22float2(*reinterpret_cast<const __half2*>(&hv7.x));
            const float2 f1 = __half22float2(*reinterpret_cast<const __half2*>(&hv7.y));
            s01.x += f0.x; s01.y += f0.y; s23.x += f1.x; s23.y += f1.y;
        }
        const float4 w = pw4[l * 32 + c];
        a01.x = fmaf(s01.x, w.x, a01.x);
        a01.y = fmaf(s01.y, w.y, a01.y);
        a23.x = fmaf(s23.x, w.z, a23.x);
        a23.y = fmaf(s23.y, w.w, a23.y);
    }
    {
        float4 r;
        r.x = a01.x * 0.125f; r.y = a01.y * 0.125f;
        r.z = a23.x * 0.125f; r.w = a23.y * 0.125f;
        sres4[node][c] = r;
    }

    // ---- phase 2: out[node][j], j = c + 32*jj, over 4 fcw k-tiles ----
    float o0 = 0.0f, o1 = 0.0f, o2 = 0.0f, o3 = 0.0f;

    #pragma unroll
    for (int kt = 0; kt < HIDDEN / KT; ++kt) {
        __syncthreads();   // protect fcwt reuse (and sres on first iter)
        {
            const int j    = tid >> 1;        // 0..127
            const int half = tid & 1;         // 0..1
            const int gbase = j * 32 + kt * (KT / 4) + half * 4;
            const int lbase = half * 16;
            #pragma unroll
            for (int q = 0; q < 4; ++q) {
                const float4 v = fcw4[gbase + q];
                fcwt[j][lbase + q * 4 + 0] = v.x;
                fcwt[j][lbase + q * 4 + 1] = v.y;
                fcwt[j][lbase + q * 4 + 2] = v.z;
                fcwt[j][lbase + q * 4 + 3] = v.w;
            }
        }
        __syncthreads();

        #pragma unroll
        for (int kc = 0; kc < KT / 4; ++kc) {
            const float4 rv = sres4[node][kt * (KT / 4) + kc];
            const int k0 = kc * 4;
            o0 = fmaf(rv.x, fcwt[c      ][k0    ], o0);
            o1 = fmaf(rv.x, fcwt[c + 32 ][k0    ], o1);
            o2 = fmaf(rv.x, fcwt[c + 64 ][k0    ], o2);
            o3 = fmaf(rv.x, fcwt[c + 96 ][k0    ], o3);
            o0 = fmaf(rv.y, fcwt[c      ][k0 + 1], o0);
            o1 = fmaf(rv.y, fcwt[c + 32 ][k0 + 1], o1);
            o2 = fmaf(rv.y, fcwt[c + 64 ][k0 + 1], o2);
            o3 = fmaf(rv.y, fcwt[c + 96 ][k0 + 1], o3);
            o0 = fmaf(rv.z, fcwt[c      ][k0 + 2], o0);
            o1 = fmaf(rv.z, fcwt[c + 32 ][k0 + 2], o1);
            o2 = fmaf(rv.z, fcwt[c + 64 ][k0 + 2], o2);
            o3 = fmaf(rv.z, fcwt[c + 96 ][k0 + 2], o3);
            o0 = fmaf(rv.w, fcwt[c      ][k0 + 3], o0);
            o1 = fmaf(rv.w, fcwt[c + 32 ][k0 + 3], o1);
            o2 = fmaf(rv.w, fcwt[c + 64 ][k0 + 3], o2);
            o3 = fmaf(rv.w, fcwt[c + 96 ][k0 + 3], o3);
        }
    }

    {
        const size_t obase = (size_t)(n0 + node) * HIDDEN + c;
        out[obase]      = o0 > 0.0f ? o0 : 0.0f;
        out[obase + 32] = o1 > 0.0f ? o1 : 0.0f;
        out[obase + 64] = o2 > 0.0f ? o2 : 0.0f;
        out[obase + 96] = o3 > 0.0f ? o3 : 0.0f;
    }
}

// ---------------- Fallback: R0's fused f32 kernel (418 us proven) ----------------
__global__ void PathGCNLayer_61306363183203_fused(
    const float4* __restrict__ feats4,
    const int*    __restrict__ paths,
    const float4* __restrict__ pw4,
    const float4* __restrict__ fcw4,
    float*        __restrict__ out)
{
    __shared__ int    sidx[NPATH * NPB * PLEN];
    __shared__ float4 sres4[NPB][33];
    __shared__ float  fcwt[HIDDEN][KT + 1];

    const int tid  = threadIdx.x;
    const int n0   = blockIdx.x * NPB;
    const int node = tid >> 5;
    const int c    = tid & 31;

    {
        const int p = tid >> 5;
        const int i = tid & 31;
        const size_t base = (size_t)p * (N_NODES * PLEN) + (size_t)n0 * PLEN;
        sidx[p * 64 + i]      = paths[base + i];
        sidx[p * 64 + i + 32] = paths[base + i + 32];
    }
    __syncthreads();

    float ax = 0.0f, ay = 0.0f, az = 0.0f, aw = 0.0f;
    #pragma unroll
    for (int l = 0; l < PLEN; ++l) {
        float sx = 0.0f, sy = 0.0f, sz = 0.0f, sw = 0.0f;
        #pragma unroll
        for (int p = 0; p < NPATH; ++p) {
            const int idx = sidx[p * 64 + node * PLEN + l];
            const float4 v = feats4[(size_t)idx * 32 + c];
            sx += v.x; sy += v.y; sz += v.z; sw += v.w;
        }
        const float4 w = pw4[l * 32 + c];
        ax = fmaf(sx, w.x, ax);
        ay = fmaf(sy, w.y, ay);
        az = fmaf(sz, w.z, az);
        aw = fmaf(sw, w.w, aw);
    }
    {
        float4 r;
        r.x = ax * 0.125f; r.y = ay * 0.125f;
        r.z = az * 0.125f; r.w = aw * 0.125f;
        sres4[node][c] = r;
    }

    float o0 = 0.0f, o1 = 0.0f, o2 = 0.0f, o3 = 0.0f;
    #pragma unroll
    for (int kt = 0; kt < HIDDEN / KT; ++kt) {
        __syncthreads();
        {
            const int j    = tid >> 1;
            const int half = tid & 1;
            const int gbase = j * 32 + kt * (KT / 4) + half * 4;
            const int lbase = half * 16;
            #pragma unroll
            for (int q = 0; q < 4; ++q) {
                const float4 v = fcw4[gbase + q];
                fcwt[j][lbase + q * 4 + 0] = v.x;
                fcwt[j][lbase + q * 4 + 1] = v.y;
                fcwt[j][lbase + q * 4 + 2] = v.z;
                fcwt[j][lbase + q * 4 + 3] = v.w;
            }
        }
        __syncthreads();
        #pragma unroll
        for (int kc = 0; kc < KT / 4; ++kc) {
            const float4 rv = sres4[node][kt * (KT / 4) + kc];
            const int k0 = kc * 4;
            o0 = fmaf(rv.x, fcwt[c      ][k0    ], o0);
            o1 = fmaf(rv.x, fcwt[c + 32 ][k0    ], o1);
            o2 = fmaf(rv.x, fcwt[c + 64 ][k0    ], o2);
            o3 = fmaf(rv.x, fcwt[c + 96 ][k0    ], o3);
            o0 = fmaf(rv.y, fcwt[c      ][k0 + 1], o0);
            o1 = fmaf(rv.y, fcwt[c + 32 ][k0 + 1], o1);
            o2 = fmaf(rv.y, fcwt[c + 64 ][k0 + 1], o2);
            o3 = fmaf(rv.y, fcwt[c + 96 ][k0 + 1], o3);
            o0 = fmaf(rv.z, fcwt[c      ][k0 + 2], o0);
            o1 = fmaf(rv.z, fcwt[c + 32 ][k0 + 2], o1);
            o2 = fmaf(rv.z, fcwt[c + 64 ][k0 + 2], o2);
            o3 = fmaf(rv.z, fcwt[c + 96 ][k0 + 2], o3);
            o0 = fmaf(rv.w, fcwt[c      ][k0 + 3], o0);
            o1 = fmaf(rv.w, fcwt[c + 32 ][k0 + 3], o1);
            o2 = fmaf(rv.w, fcwt[c + 64 ][k0 + 3], o2);
            o3 = fmaf(rv.w, fcwt[c + 96 ][k0 + 3], o3);
        }
    }
    {
        const size_t obase = (size_t)(n0 + node) * HIDDEN + c;
        out[obase]      = o0 > 0.0f ? o0 : 0.0f;
        out[obase + 32] = o1 > 0.0f ? o1 : 0.0f;
        out[obase + 64] = o2 > 0.0f ? o2 : 0.0f;
        out[obase + 96] = o3 > 0.0f ? o3 : 0.0f;
    }
}

extern "C" void kernel_launch(void* const* d_in, const int* in_sizes, int n_in,
                              void* d_out, int out_size, void* d_ws, size_t ws_size,
                              hipStream_t stream) {
    const float4* feats4 = (const float4*)d_in[0];  // (N,128) f32
    const int*    paths  = (const int*)d_in[1];     // (8,N,8) int32
    // d_in[2] = init_feats — unused by the reference
    const float4* pw4    = (const float4*)d_in[3];  // (1,8,128) f32
    const float4* fcw4   = (const float4*)d_in[4];  // (128,128) f32
    float* out = (float*)d_out;
    (void)in_sizes; (void)n_in; (void)out_size;

    const size_t half_bytes = (size_t)N_NODES * HIDDEN * sizeof(unsigned short); // 25.6 MB
    if (d_ws != nullptr && ws_size >= half_bytes) {
        uint2* fh = (uint2*)d_ws;
        const int cvt_blocks = (N_NODES * 32 + 255) / 256;   // 3.2M float4s
        PathGCNLayer_61306363183203_tohalf<<<cvt_blocks, 256, 0, stream>>>(feats4, fh);
        PathGCNLayer_61306363183203_fused_h<<<N_NODES / NPB, 256, 0, stream>>>(
            fh, paths, pw4, fcw4, out);
    } else {
        PathGCNLayer_61306363183203_fused<<<N_NODES / NPB, 256, 0, stream>>>(
            feats4, paths, pw4, fcw4, out);
    }
}